// Round 4
// baseline (285.094 us; speedup 1.0000x reference)
//
#include <hip/hip_runtime.h>

// ROI Align (FPN multi-level), OUT=7, ratio=2.
// Round-8: still latency-bound (VALU 22%, HBM 15%, occ 38%). Waves die after
// one issue->waitcnt(0)->compute chain; nothing overlaps the memory RT.
// Fix: 4 channels of one ROI per wave, two-phase intra-wave pipeline with
// COUNTED vmcnt: issue A (c0,c1; natural count), issue B (c2,c3; padded to
// exactly 2*ITMAX=10 loads, dummies -> LDS dump row), s_waitcnt vmcnt(10)
// retires A while B stays in flight, compute A, vmcnt(0), compute B, store 4.
// B's flight hides under A's compute; table RT amortized over 4 units.
// Also fixes latent staging overflow: safe now requires iters*rpi*RS4 <= CAP
// (old check allowed writes past CAP into the neighbor wave's LDS region).
// LDS 38.9KB/block (128-thr, 2 waves) -> 4 blocks/CU -> 8 waves/CU.

#define NCH 256
#define POOL 7
#define NBIN 49
#define CAP 1152          // floats per unit footprint region
#define WPB 2             // waves per main-kernel block (128 threads)
#define PWPB 4            // waves per precompute block (256 threads)
#define TS 128            // u32 words per ROI table entry (512 B)
#define ITMAX 5           // max staging iterations on the safe path
#define UPW 4             // units (channels) per wave
#define DUMPF (UPW * CAP) // dump row float offset (256 floats = 64 lanes x 16B)

typedef __attribute__((address_space(3))) void       as3_void;
typedef __attribute__((address_space(1))) const void as1_void;

// ---------------------------------------------------------------------------
// Per-ROI precompute: one wave per ROI. Writes tab[m*TS .. m*TS+127]:
//  [0] base_off (elems, c=0)   [1] lvl      [2] HW        [3] W
//  [4] lpr                     [5] Mg=ceil(65536/lpr)     [6] rpi=64/lpr
//  [7] iters                   [8] gstep=rpi*W (elems)    [9] lstepB=rpi*RS4*4
//  [10] (FH-1)*W               [11] safe    [12] FW       [13] RS4
//  [14] FH2 (fallback rows)    [15] Mg2=ceil(2^22/RS4)
//  [16..71]  xtab[14] uint4: {xr, xp=min(xr+1,FW-1), wxl, wxh}   (elems)
//  [72..127] ytab[14] uint4: {(ylo-ry0)*RS4, (yhi-ry0)*RS4, wyl, wyh}
// ---------------------------------------------------------------------------
__global__ __launch_bounds__(256) void roi_precompute_kernel(
    const float* __restrict__ boxes, const int* __restrict__ bidx,
    unsigned int* __restrict__ tab, int M)
{
    const int lane = threadIdx.x & 63;
    const int m = blockIdx.x * PWPB + (threadIdx.x >> 6);
    if (m >= M) return;

    float bx0 = boxes[4 * m + 0];
    float by0 = boxes[4 * m + 1];
    float bx1 = boxes[4 * m + 2];
    float by1 = boxes[4 * m + 3];

    float area = (bx1 - bx0) * (by1 - by0);
    float sz   = sqrtf(area);
    float lvlf = floorf(4.0f + log2f(sz / 224.0f + 1e-8f));
    lvlf = fminf(fmaxf(lvlf, 2.0f), 5.0f);
    int lvl = (int)lvlf - 2;

    int H, W; float scale;
    if (lvl == 0)      { H = 200; W = 304; scale = 0.25f;    }
    else if (lvl == 1) { H = 100; W = 152; scale = 0.125f;   }
    else if (lvl == 2) { H = 50;  W = 76;  scale = 0.0625f;  }
    else               { H = 25;  W = 38;  scale = 0.03125f; }

    float x0 = bx0 * scale - 0.5f;
    float y0 = by0 * scale - 0.5f;
    float bin_w = (bx1 * scale - 0.5f - x0) * (1.0f / 7.0f);
    float bin_h = (by1 * scale - 0.5f - y0) * (1.0f / 7.0f);

    // lanes 0..13: x samples; lanes 14..27: y samples (28..63 compute garbage,
    // never read: shfl sources and writes stay within lanes 0..27)
    int axis = lane >= 14;
    int s    = axis ? (lane - 14) : lane;
    float off = (float)(s >> 1) + ((s & 1) ? 0.75f : 0.25f);
    float cv    = axis ? (y0 + bin_h * off) : (x0 + bin_w * off);
    float size  = axis ? (float)H : (float)W;
    float valid = (cv >= -1.0f && cv <= size) ? 1.0f : 0.0f;
    float cc    = fmaxf(cv, 0.0f);
    float lo_f  = floorf(cc);
    bool  capd  = lo_f >= size - 1.0f;
    int   lo    = capd ? (int)size - 1 : (int)lo_f;
    int   hi    = capd ? lo : lo + 1;
    float l     = capd ? 0.0f : (cc - lo_f);
    float wlo   = (1.0f - l) * valid;
    float whi   = l * valid;

    int rx0 = __shfl(lo, 0);
    int rxe = __shfl(hi, 13);
    int ry0 = __shfl(lo, 14);
    int rye = __shfl(hi, 27);

    int FW  = rxe - rx0 + 1;
    int FH  = rye - ry0 + 1;
    int lpr = (FW + 3) >> 2;
    int RS4 = lpr << 2;
    int rpi = 64 / lpr;
    int iters = (FH + rpi - 1) / rpi;
    unsigned Mg  = (65536u   + (unsigned)lpr - 1u) / (unsigned)lpr;
    unsigned Mg2 = (4194304u + (unsigned)RS4 - 1u) / (unsigned)RS4;
    unsigned HW  = (unsigned)(H * W);
    unsigned base_off = (unsigned)bidx[m] * 256u * HW
                      + (unsigned)ry0 * (unsigned)W + (unsigned)rx0;
    int FH2 = FH;
    if (FH2 * RS4 > CAP) FH2 = CAP / RS4;
    // safe for ALL channels iff safe for c=255 (largest offset).
    // iters*rpi*RS4 <= CAP: the padded write extent (ceil(FH/rpi)*rpi rows)
    // must fit the unit region (fixes latent overflow into neighbor wave).
    // iters <= ITMAX: phase-B padding bound on the counted-vmcnt path.
    unsigned lastoff = base_off + 255u * HW
                     + (unsigned)(FH - 1) * (unsigned)W + (unsigned)RS4;
    int safe = (lastoff <= 2u * 256u * HW)
            && (iters * rpi * RS4 <= CAP)
            && (iters <= ITMAX);

    unsigned* t = tab + (size_t)m * TS;
    if (lane == 0) {
        t[0]  = base_off;
        t[1]  = (unsigned)lvl;
        t[2]  = HW;
        t[3]  = (unsigned)W;
        t[4]  = (unsigned)lpr;
        t[5]  = Mg;
        t[6]  = (unsigned)rpi;
        t[7]  = (unsigned)iters;
        t[8]  = (unsigned)(rpi * W);
        t[9]  = (unsigned)((rpi * RS4) << 2);
        t[10] = (unsigned)((FH - 1) * W);
        t[11] = (unsigned)safe;
        t[12] = (unsigned)FW;
        t[13] = (unsigned)RS4;
        t[14] = (unsigned)FH2;
        t[15] = Mg2;
    }
    if (lane < 28) {
        if (!axis) {
            int xr = lo - rx0;
            int xp = min(xr + 1, FW - 1);   // cap-x: weight is 0, stay in row
            uint4 v;
            v.x = (unsigned)xr;
            v.y = (unsigned)xp;
            v.z = __float_as_uint(wlo);
            v.w = __float_as_uint(whi);
            *(uint4*)(t + 16 + 4 * s) = v;
        } else {
            uint4 v;
            v.x = (unsigned)((lo - ry0) * RS4);
            v.y = (unsigned)((hi - ry0) * RS4);
            v.z = __float_as_uint(wlo);
            v.w = __float_as_uint(whi);
            *(uint4*)(t + 72 + 4 * s) = v;
        }
    }
}

// one unit's 49-bin bilinear sample from LDS
#define BILIN(Fb, ACC) do {                                                 \
    float a0_ = Fb[ra + xr0] * wxl0 + Fb[ra + xp0] * wxh0                   \
              + Fb[ra + xr1] * wxl1 + Fb[ra + xp1] * wxh1;                  \
    float a1_ = Fb[rb2 + xr0] * wxl0 + Fb[rb2 + xp0] * wxh0                 \
              + Fb[rb2 + xr1] * wxl1 + Fb[rb2 + xp1] * wxh1;                \
    float a2_ = Fb[rc + xr0] * wxl0 + Fb[rc + xp0] * wxh0                   \
              + Fb[rc + xr1] * wxl1 + Fb[rc + xp1] * wxh1;                  \
    float a3_ = Fb[rd + xr0] * wxl0 + Fb[rd + xp0] * wxh0                   \
              + Fb[rd + xr1] * wxl1 + Fb[rd + xp1] * wxh1;                  \
    ACC = wy0 * a0_ + wy1 * a1_ + wy2 * a2_ + wy3 * a3_;                    \
} while (0)

// ---------------------------------------------------------------------------
// Main kernel: 4 channels of one ROI per wave, two-phase counted-vmcnt
// pipeline; c-major order with XCD channel-quad chunking.
// ---------------------------------------------------------------------------
__global__ __launch_bounds__(128, 2) void roi_align_kernel(
    const float* __restrict__ f0, const float* __restrict__ f1,
    const float* __restrict__ f2, const float* __restrict__ f3,
    const unsigned int* __restrict__ tab,
    float* __restrict__ out, int M)
{
    __shared__ float sF[WPB][UPW * CAP + 256];

    const int lane = threadIdx.x & 63;
    const int w    = __builtin_amdgcn_readfirstlane(threadIdx.x >> 6);

    // grid = mblocks * 64 (divisible by 8)
    const unsigned mblocks = (unsigned)gridDim.x >> 6;
    const unsigned rb   = blockIdx.x;
    const unsigned xcd  = rb & 7u;
    const unsigned idx  = rb >> 3;                 // 0 .. mblocks*8-1
    const unsigned qblk = idx / mblocks;           // 0..7 (once per block)
    const unsigned mb   = idx - qblk * mblocks;
    const int c0 = (int)((xcd * 8u + qblk) * 4u);  // first channel of quad
    const int m  = (int)(mb * WPB) + w;
    if (m >= M) return;

    const unsigned* t = tab + (size_t)m * TS;

    // ---- per-lane geometry: shared by all 4 units (same ROI) ----
    const int ci = lane < NBIN ? lane : 0;         // clamp lanes 49..63
    const int py = ci / POOL;                      // const-div -> magic
    const int px = ci - POOL * py;
    const uint4* xt = (const uint4*)(t + 16);
    const uint4* yt = (const uint4*)(t + 72);
    const uint4 X0 = xt[2 * px];
    const uint4 X1 = xt[2 * px + 1];
    const uint4 Y0 = yt[2 * py];
    const uint4 Y1 = yt[2 * py + 1];

    // ---- wave-uniform staging scalars ----
    const uint4 s0 = *(const uint4*)(t);           // base_off, lvl, HW, W
    const uint4 s1 = *(const uint4*)(t + 4);       // lpr, Mg, rpi, iters
    const uint4 s2 = *(const uint4*)(t + 8);       // gstep, lstepB, fhw, safe

    const int lvl = __builtin_amdgcn_readfirstlane((int)s0.y);
    const float* fp = (lvl == 0) ? f0 : (lvl == 1) ? f1 : (lvl == 2) ? f2 : f3;
    const unsigned HW = s0.z;
    const unsigned Wd = s0.w;
    const float* src0 = fp + (size_t)(s0.x + (unsigned)c0 * HW);

    // weight unpack (used by both paths)
    const unsigned xr0 = X0.x, xp0 = X0.y, xr1 = X1.x, xp1 = X1.y;
    const float wxl0 = __uint_as_float(X0.z), wxh0 = __uint_as_float(X0.w);
    const float wxl1 = __uint_as_float(X1.z), wxh1 = __uint_as_float(X1.w);
    const unsigned ra = Y0.x, rb2 = Y0.y, rc = Y1.x, rd = Y1.y;
    const float wy0 = __uint_as_float(Y0.z), wy1 = __uint_as_float(Y0.w);
    const float wy2 = __uint_as_float(Y1.z), wy3 = __uint_as_float(Y1.w);

    const float* Fb0 = &sF[w][0];
    const float* Fb1 = &sF[w][CAP];
    const float* Fb2 = &sF[w][2 * CAP];
    const float* Fb3 = &sF[w][3 * CAP];
    float acc0, acc1, acc2, acc3;

    const int safe = __builtin_amdgcn_readfirstlane((int)s2.w);
    if (safe) {
        const int lpr      = __builtin_amdgcn_readfirstlane((int)s1.x);
        const unsigned Mg  = s1.y;
        const int rpi      = __builtin_amdgcn_readfirstlane((int)s1.z);
        const int iters    = __builtin_amdgcn_readfirstlane((int)s1.w);
        const unsigned gstep  = s2.x;              // elems
        const unsigned lstepB = __builtin_amdgcn_readfirstlane((int)s2.y);
        const unsigned fhw    = s2.z;              // (FH-1)*W elems

        int sfy  = (int)(((unsigned)lane * Mg) >> 16);   // lane / lpr, exact
        int sfx4 = (lane - sfy * lpr) << 2;
        const unsigned lo0 = (unsigned)sfy * Wd + (unsigned)sfx4;
        const unsigned hi0 = fhw + (unsigned)sfx4;
        const bool act = sfy < rpi;

        // ---- phase A issue: units 0,1 (count irrelevant; retired below) ----
        if (act) {
            const float* gA  = src0 + lo0;
            const float* gB  = src0 + HW + lo0;
            const float* gmA = src0 + hi0;
            const float* gmB = src0 + HW + hi0;
            char* lA = (char*)Fb0;                 // uniform; HW adds lane*16
            char* lB = (char*)Fb1;
            for (int it = 0; it < iters; ++it) {
                const float* pa = (gA > gmA) ? gmA : gA;   // pad rows reload
                const float* pb = (gB > gmB) ? gmB : gB;
                __builtin_amdgcn_global_load_lds((as1_void*)pa,
                                                 (as3_void*)lA, 16, 0, 0);
                __builtin_amdgcn_global_load_lds((as1_void*)pb,
                                                 (as3_void*)lB, 16, 0, 0);
                gA += gstep; gB += gstep; lA += lstepB; lB += lstepB;
            }
        }
        __builtin_amdgcn_sched_barrier(0);   // A-loads may not mix into B
        // ---- phase B issue: units 2,3, padded to EXACTLY 2*ITMAX loads ----
        if (act) {
            const float* gC  = src0 + 2u * HW + lo0;
            const float* gD  = src0 + 3u * HW + lo0;
            const float* gmC = src0 + 2u * HW + hi0;
            const float* gmD = src0 + 3u * HW + hi0;
            char* lC = (char*)Fb2;
            char* lD = (char*)Fb3;
            char* dmp = (char*)&sF[w][DUMPF];      // 1KB wave scratch
            #pragma unroll
            for (int it = 0; it < ITMAX; ++it) {
                const float* pc = (gC > gmC) ? gmC : gC;
                const float* pd = (gD > gmD) ? gmD : gD;
                char* wc = (it < iters) ? lC : dmp;    // dummies -> dump row
                char* wd = (it < iters) ? lD : dmp;
                __builtin_amdgcn_global_load_lds((as1_void*)pc,
                                                 (as3_void*)wc, 16, 0, 0);
                __builtin_amdgcn_global_load_lds((as1_void*)pd,
                                                 (as3_void*)wd, 16, 0, 0);
                gC += gstep; gD += gstep; lC += lstepB; lD += lstepB;
            }
        }
        // retire A (+tables); leave exactly phase B's 10 loads in flight
        static_assert(2 * ITMAX == 10, "update vmcnt immediate");
        asm volatile("s_waitcnt vmcnt(10)" ::: "memory");
        __builtin_amdgcn_sched_barrier(0);

        BILIN(Fb0, acc0);                          // compute A under B flight
        BILIN(Fb1, acc1);

        asm volatile("s_waitcnt vmcnt(0)" ::: "memory");
        __builtin_amdgcn_sched_barrier(0);

        BILIN(Fb2, acc2);
        BILIN(Fb3, acc3);
    } else {
        // rare fallback (tail window / oversize / iters>ITMAX): scalar stage
        const uint4 s3 = *(const uint4*)(t + 12);  // FW, RS4, FH2, Mg2
        const int FW  = __builtin_amdgcn_readfirstlane((int)s3.x);
        const int RS4 = __builtin_amdgcn_readfirstlane((int)s3.y);
        const int FH2 = __builtin_amdgcn_readfirstlane((int)s3.z);
        const unsigned Mg2 = s3.w;
        const int tot = FH2 * RS4;
        for (int i = lane; i < tot; i += 64) {
            int fy = (int)(((unsigned)i * Mg2) >> 22);   // i / RS4, exact
            int fx = i - fy * RS4;
            int cx = fx < FW ? fx : FW - 1;
            unsigned goff = (unsigned)fy * Wd + (unsigned)cx;
            sF[w][i]           = src0[goff];
            sF[w][CAP + i]     = src0[HW + goff];
            sF[w][2 * CAP + i] = src0[2u * HW + goff];
            sF[w][3 * CAP + i] = src0[3u * HW + goff];
        }
        __builtin_amdgcn_s_waitcnt(0);
        __asm__ __volatile__("" ::: "memory");
        BILIN(Fb0, acc0);
        BILIN(Fb1, acc1);
        BILIN(Fb2, acc2);
        BILIN(Fb3, acc3);
    }

    if (lane < NBIN) {
        size_t ob = ((size_t)m * NCH + (unsigned)c0) * NBIN + (unsigned)lane;
        out[ob]            = acc0 * 0.25f;
        out[ob + NBIN]     = acc1 * 0.25f;
        out[ob + 2 * NBIN] = acc2 * 0.25f;
        out[ob + 3 * NBIN] = acc3 * 0.25f;
    }
}

extern "C" void kernel_launch(void* const* d_in, const int* in_sizes, int n_in,
                              void* d_out, int out_size, void* d_ws, size_t ws_size,
                              hipStream_t stream) {
    const float* f0    = (const float*)d_in[0];
    const float* f1    = (const float*)d_in[1];
    const float* f2    = (const float*)d_in[2];
    const float* f3    = (const float*)d_in[3];
    const float* boxes = (const float*)d_in[4];
    const int*   bidx  = (const int*)d_in[5];
    float* out = (float*)d_out;

    int M = in_sizes[4] / 4;
    unsigned int* tab = (unsigned int*)d_ws;          // M * 512 B

    int pblocks = (M + PWPB - 1) / PWPB;
    hipLaunchKernelGGL(roi_precompute_kernel, dim3(pblocks), dim3(256), 0,
                       stream, boxes, bidx, tab, M);

    int mblocks = (M + WPB - 1) / WPB;
    int blocks = mblocks * (NCH / UPW);               // 4 channels per wave
    hipLaunchKernelGGL(roi_align_kernel, dim3(blocks), dim3(128), 0, stream,
                       f0, f1, f2, f3, tab, out, M);
}